// Round 3
// baseline (135.718 us; speedup 1.0000x reference)
//
#include <hip/hip_runtime.h>

// Problem constants (from reference setup_inputs):
// heat_preds / heatmaps: [S=5, B=16, C=11, H=128, W=128] f32
// label_preds: [S, B, NCLASS=11, F=7] f32 ; labels: [B, 11, 7] f32
// Outputs (concatenated flat): combined_loss [B,S] then labels_loss [B,S] -> 160 f32
#define SS 5
#define BB 16
#define CC 11
#define HW 16384       // 128*128
#define CF 77          // 11*7
#define CHUNK 4096     // floats per partial block
#define NCHUNK 4       // chunks per (s,b,c) slice = HW/CHUNK
#define NPART (SS * BB * CC * NCHUNK)   // 3520 partial blocks
#define PPO (CC * NCHUNK)               // partials per output (s,b) = 44

// Kernel A: one block per 4096-float chunk, sum of squared diffs -> partials[blk].
// All 8 float4 loads are issued before any use (explicit registers) so the wave
// has 8 vector loads in flight instead of the 2 the 36-VGPR version managed.
// ~55 VGPRs keeps full 32-wave/CU occupancy (cliff is at 64).
__global__ __launch_bounds__(256) void heat_partial_kernel(const float* __restrict__ hp,
                                                           const float* __restrict__ hm,
                                                           float* __restrict__ partials) {
    const int blk = blockIdx.x;
    const size_t base = (size_t)blk * CHUNK;
    const float4* __restrict__ p = (const float4*)(hp + base);
    const float4* __restrict__ q = (const float4*)(hm + base);

    const int t = threadIdx.x;

    // Batch-issue all loads (independent addresses, no use until all issued).
    float4 a0 = p[t];
    float4 a1 = p[t + 256];
    float4 a2 = p[t + 512];
    float4 a3 = p[t + 768];
    float4 m0 = q[t];
    float4 m1 = q[t + 256];
    float4 m2 = q[t + 512];
    float4 m3 = q[t + 768];

    float s0 = 0.0f, s1 = 0.0f, s2 = 0.0f, s3 = 0.0f;
    {
        float d;
        d = a0.x - m0.x; s0 += d * d;
        d = a0.y - m0.y; s1 += d * d;
        d = a0.z - m0.z; s2 += d * d;
        d = a0.w - m0.w; s3 += d * d;
        d = a1.x - m1.x; s0 += d * d;
        d = a1.y - m1.y; s1 += d * d;
        d = a1.z - m1.z; s2 += d * d;
        d = a1.w - m1.w; s3 += d * d;
        d = a2.x - m2.x; s0 += d * d;
        d = a2.y - m2.y; s1 += d * d;
        d = a2.z - m2.z; s2 += d * d;
        d = a2.w - m2.w; s3 += d * d;
        d = a3.x - m3.x; s0 += d * d;
        d = a3.y - m3.y; s1 += d * d;
        d = a3.z - m3.z; s2 += d * d;
        d = a3.w - m3.w; s3 += d * d;
    }
    float sum = (s0 + s1) + (s2 + s3);

#pragma unroll
    for (int off = 32; off > 0; off >>= 1) sum += __shfl_down(sum, off, 64);

    __shared__ float wsum[4];
    const int lane = t & 63;
    const int wave = t >> 6;
    if (lane == 0) wsum[wave] = sum;
    __syncthreads();
    if (t == 0) partials[blk] = wsum[0] + wsum[1] + wsum[2] + wsum[3];
}

// Kernel B: one 64-lane block per output (s,b). Reduces the 44 contiguous
// partials and fuses the labels loss. No atomics, no zero-init needed.
__global__ __launch_bounds__(64) void final_kernel(const float* __restrict__ partials,
                                                   const float* __restrict__ label_preds,
                                                   const float* __restrict__ labels,
                                                   float* __restrict__ out) {
    const int sb = blockIdx.x;   // s*BB + b
    const int s = sb / BB;
    const int b = sb % BB;
    const int lane = threadIdx.x;

    float h = (lane < PPO) ? partials[sb * PPO + lane] : 0.0f;

    const float* lp = label_preds + (size_t)sb * CF;
    const float* lb = labels + (size_t)b * CF;
    float l = 0.0f;
    {
        float d = lp[lane] - lb[lane];   // lane < 77 always (64 < 77)
        l = d * d;
    }
    const int i2 = lane + 64;
    if (i2 < CF) {  // lanes 0..12 take elements 64..76
        float d = lp[i2] - lb[i2];
        l += d * d;
    }

#pragma unroll
    for (int off = 32; off > 0; off >>= 1) {
        h += __shfl_down(h, off, 64);
        l += __shfl_down(l, off, 64);
    }

    if (lane == 0) {
        out[b * SS + s] = h * (1.0f / (float)HW);   // combined_loss [B,S]
        out[SS * BB + b * SS + s] = l;              // labels_loss   [B,S]
    }
}

extern "C" void kernel_launch(void* const* d_in, const int* in_sizes, int n_in,
                              void* d_out, int out_size, void* d_ws, size_t ws_size,
                              hipStream_t stream) {
    const float* heat_preds = (const float*)d_in[0];
    const float* heatmaps = (const float*)d_in[1];
    const float* label_preds = (const float*)d_in[2];
    const float* labels = (const float*)d_in[3];
    float* out = (float*)d_out;
    float* partials = (float*)d_ws;  // 3520 floats = 14 KB

    heat_partial_kernel<<<NPART, 256, 0, stream>>>(heat_preds, heatmaps, partials);
    final_kernel<<<SS * BB, 64, 0, stream>>>(partials, label_preds, labels, out);
}

// Round 4
// 132.184 us; speedup vs baseline: 1.0267x; 1.0267x over previous
//
#include <hip/hip_runtime.h>

// Problem constants (from reference setup_inputs):
// heat_preds / heatmaps: [S=5, B=16, C=11, H=128, W=128] f32
// label_preds: [S, B, NCLASS=11, F=7] f32 ; labels: [B, 11, 7] f32
// Outputs (concatenated flat): combined_loss [B,S] then labels_loss [B,S] -> 160 f32
#define SS 5
#define BB 16
#define CC 11
#define HW 16384       // 128*128
#define CF 77          // 11*7
#define CHUNK 2048     // floats per partial block
#define NCHUNK 8       // chunks per (s,b,c) slice = HW/CHUNK
#define NPART (SS * BB * CC * NCHUNK)   // 7040 partial blocks
#define PPO (CC * NCHUNK)               // partials per output (s,b) = 88

// Kernel A: one block per 2048-float chunk, sum of squared diffs -> partials[blk].
// 7040 blocks x 256 threads = 27.5 blocks/CU: doubles wave-starts vs the 3520-block
// version to shrink the dispatch/drain tail; 4 loads batch-issued per thread keeps
// MLP while VGPR stays low (~28) for full occupancy.
__global__ __launch_bounds__(256) void heat_partial_kernel(const float* __restrict__ hp,
                                                           const float* __restrict__ hm,
                                                           float* __restrict__ partials) {
    const int blk = blockIdx.x;
    const size_t base = (size_t)blk * CHUNK;
    const float4* __restrict__ p = (const float4*)(hp + base);
    const float4* __restrict__ q = (const float4*)(hm + base);

    const int t = threadIdx.x;

    // Batch-issue all 4 loads (independent addresses) before any use.
    float4 a0 = p[t];
    float4 a1 = p[t + 256];
    float4 m0 = q[t];
    float4 m1 = q[t + 256];

    float s0, s1, s2, s3;
    float d;
    d = a0.x - m0.x; s0 = d * d;
    d = a0.y - m0.y; s1 = d * d;
    d = a0.z - m0.z; s2 = d * d;
    d = a0.w - m0.w; s3 = d * d;
    d = a1.x - m1.x; s0 += d * d;
    d = a1.y - m1.y; s1 += d * d;
    d = a1.z - m1.z; s2 += d * d;
    d = a1.w - m1.w; s3 += d * d;
    float sum = (s0 + s1) + (s2 + s3);

#pragma unroll
    for (int off = 32; off > 0; off >>= 1) sum += __shfl_down(sum, off, 64);

    __shared__ float wsum[4];
    const int lane = t & 63;
    const int wave = t >> 6;
    if (lane == 0) wsum[wave] = sum;
    __syncthreads();
    if (t == 0) partials[blk] = wsum[0] + wsum[1] + wsum[2] + wsum[3];
}

// Kernel B: one 64-lane block per output (s,b). Reduces the 88 contiguous
// partials (lanes cover i and i+64) and fuses the labels loss. No atomics.
__global__ __launch_bounds__(64) void final_kernel(const float* __restrict__ partials,
                                                   const float* __restrict__ label_preds,
                                                   const float* __restrict__ labels,
                                                   float* __restrict__ out) {
    const int sb = blockIdx.x;   // s*BB + b
    const int s = sb / BB;
    const int b = sb % BB;
    const int lane = threadIdx.x;

    const float* pp = partials + (size_t)sb * PPO;
    float h = pp[lane % PPO] * (lane < PPO ? 1.0f : 0.0f);
    h = (lane < PPO) ? pp[lane] : 0.0f;
    const int j2 = lane + 64;
    if (j2 < PPO) h += pp[j2];   // lanes 0..23 take partials 64..87

    const float* lp = label_preds + (size_t)sb * CF;
    const float* lb = labels + (size_t)b * CF;
    float dd = lp[lane] - lb[lane];   // lane < 77 always (64 < 77)
    float l = dd * dd;
    const int i2 = lane + 64;
    if (i2 < CF) {  // lanes 0..12 take elements 64..76
        float d2 = lp[i2] - lb[i2];
        l += d2 * d2;
    }

#pragma unroll
    for (int off = 32; off > 0; off >>= 1) {
        h += __shfl_down(h, off, 64);
        l += __shfl_down(l, off, 64);
    }

    if (lane == 0) {
        out[b * SS + s] = h * (1.0f / (float)HW);   // combined_loss [B,S]
        out[SS * BB + b * SS + s] = l;              // labels_loss   [B,S]
    }
}

extern "C" void kernel_launch(void* const* d_in, const int* in_sizes, int n_in,
                              void* d_out, int out_size, void* d_ws, size_t ws_size,
                              hipStream_t stream) {
    const float* heat_preds = (const float*)d_in[0];
    const float* heatmaps = (const float*)d_in[1];
    const float* label_preds = (const float*)d_in[2];
    const float* labels = (const float*)d_in[3];
    float* out = (float*)d_out;
    float* partials = (float*)d_ws;  // 7040 floats = 28 KB

    heat_partial_kernel<<<NPART, 256, 0, stream>>>(heat_preds, heatmaps, partials);
    final_kernel<<<SS * BB, 64, 0, stream>>>(partials, label_preds, labels, out);
}